// Round 7
// baseline (230.852 us; speedup 1.0000x reference)
//
#include <hip/hip_runtime.h>
#include <math.h>

typedef unsigned int uint;
typedef unsigned short ushort;
typedef __attribute__((ext_vector_type(8))) short bf16x8;
typedef __attribute__((ext_vector_type(4))) float f32x4;

static constexpr int Mdim = 4096;
static constexpr int Ndim = 4096;
static constexpr int Kdim = 4096;
static constexpr int Hdim = 4096;

// ---------------- numerics helpers ----------------

__device__ __forceinline__ float fp8_round(float v) {
  float a = fabsf(v);
  float q;
  if (a >= 0x1p-6f) {
    uint u = __float_as_uint(a);
    int e = (int)(u >> 23) - 127;
    float quant = __uint_as_float((uint)(e - 3 + 127) << 23);
    q = rintf(a / quant) * quant;
    q = fminf(q, 448.f);
  } else {
    q = rintf(a * 512.f) * 0x1p-9f;
  }
  return copysignf(q, v);
}

__device__ __forceinline__ float e2m1_round(float t) {
  float a = fabsf(t);
  float q;
  if (a <= 0.25f) q = 0.f;
  else if (a <= 0.75f) q = 0.5f;
  else if (a <= 1.25f) q = 1.f;
  else if (a <= 1.75f) q = 1.5f;
  else if (a <= 2.5f)  q = 2.f;
  else if (a <= 3.5f)  q = 3.f;
  else if (a <= 5.f)   q = 4.f;
  else                 q = 6.f;
  return copysignf(q, t);
}

__device__ __forceinline__ float e2m1_decode(uint c) {
  uint m = c & 7u;
  float v;
  if (m == 0u) v = 0.f;
  else if (m == 1u) v = 0.5f;
  else v = __uint_as_float(((126u + (m >> 1)) << 23) | ((m & 1u) << 22));
  return (c & 8u) ? -v : v;
}

// ---------------- kernel 1: SiLU-mul + NVFP4 fake-quant -> bf16 a_deq ----------------

__global__ void silu_quant_kernel(const float* __restrict__ x, ushort* __restrict__ a_deq,
                                  const float* __restrict__ scalep) {
  const int g = blockIdx.x * 256 + threadIdx.x;
  const int row = g >> 8;
  const int blk = g & 255;
  const float gs = 1.0f / scalep[0];
  const float c6 = gs / 6.0f;
  const float* gp = x + (size_t)row * (2 * Hdim) + blk * 16;
  const float* up = gp + Hdim;
  float y[16];
  float amax = 0.f;
#pragma unroll
  for (int i = 0; i < 4; ++i) {
    float4 gv = ((const float4*)gp)[i];
    float4 uv = ((const float4*)up)[i];
    float ga[4] = {gv.x, gv.y, gv.z, gv.w};
    float ua[4] = {uv.x, uv.y, uv.z, uv.w};
#pragma unroll
    for (int j = 0; j < 4; ++j) {
      float xv = ga[j];
      float sig = 1.0f / (1.0f + expf(-xv));
      float yy = xv * sig * ua[j];
      y[i * 4 + j] = yy;
      amax = fmaxf(amax, fabsf(yy));
    }
  }
  const float sf = fp8_round(amax * c6);
  uint outp[8];
  if (sf > 0.f) {
    const float inv = gs / sf;
#pragma unroll
    for (int i = 0; i < 8; ++i) {
      float t0 = fminf(fmaxf(y[2 * i] * inv, -6.f), 6.f);
      float t1 = fminf(fmaxf(y[2 * i + 1] * inv, -6.f), 6.f);
      float d0 = e2m1_round(t0) * sf;
      float d1 = e2m1_round(t1) * sf;
      outp[i] = (__float_as_uint(d0) >> 16) | ((__float_as_uint(d1) >> 16) << 16);
    }
  } else {
#pragma unroll
    for (int i = 0; i < 8; ++i) outp[i] = 0u;
  }
  uint4* dst = (uint4*)(a_deq + (size_t)row * Hdim + blk * 16);
  dst[0] = (uint4){outp[0], outp[1], outp[2], outp[3]};
  dst[1] = (uint4){outp[4], outp[5], outp[6], outp[7]};
}

// ---------------- kernel 2: weight dequant -> bf16 b_deq ----------------

__global__ void wdeq_kernel(const int* __restrict__ w, const float* __restrict__ wscale,
                            ushort* __restrict__ b_deq) {
  const int g = blockIdx.x * 256 + threadIdx.x;
  const int n = g >> 8;
  const int blk = g & 255;
  const int4* wp = (const int4*)(w + (size_t)n * (Hdim / 2) + blk * 8);
  int4 w0 = wp[0], w1 = wp[1];
  int wb[8] = {w0.x, w0.y, w0.z, w0.w, w1.x, w1.y, w1.z, w1.w};
  const float ws = fp8_round(wscale[(size_t)n * (Hdim / 16) + blk]);
  uint outp[8];
#pragma unroll
  for (int i = 0; i < 8; ++i) {
    uint byte = (uint)wb[i] & 0xFFu;
    float vlo = e2m1_decode(byte & 15u) * ws;
    float vhi = e2m1_decode(byte >> 4) * ws;
    outp[i] = (__float_as_uint(vlo) >> 16) | ((__float_as_uint(vhi) >> 16) << 16);
  }
  uint4* dst = (uint4*)(b_deq + (size_t)n * Hdim + blk * 16);
  dst[0] = (uint4){outp[0], outp[1], outp[2], outp[3]};
  dst[1] = (uint4){outp[4], outp[5], outp[6], outp[7]};
}

// ---------------- kernel 3: 256x256 bf16 GEMM, counted-lgkmcnt pipelined schedule ----------------
// 8 waves (2M x 4N), BK=64, 2-slot LDS (128 KiB). KEY CHANGE vs rounds 2-6:
// every fragment is ds_read ONE PHASE BEFORE its MFMA uses it, and the wait is a
// COUNTED lgkmcnt(N) (N = reads just issued this phase) instead of lgkmcnt(0).
// The wait therefore only forces the PREVIOUS phase's reads (which had a whole
// MFMA cluster to complete) -> near-zero stall -> the DS pipe serves phase p+1's
// reads WHILE the matrix pipe runs phase p's MFMAs. One barrier per phase.
// Per K-tile u: q0 reads af1, q1 af2, q2 af3, q3 reads bfr'(u+1)(8)+af0'(u+1)(4)
// (legal: vmcnt(2)+barrier at q2 published A(u+1),B(u+1) to all waves).
// Waits: lgkm(4)/lgkm(4)/lgkm(4)/lgkm(12). bfr needs 2 register sets (bfrE/bfrO,
// tile parity) -> K-loop unrolled x2 with static names (no dynamic reg indexing).
// Stage ledger (tile u): q0 A(u+1)h0, q1 A(u+1)h1, q2 B(u+2)h0, q3 B(u+2)h1.
// vmcnt(2) at q2-end: outstanding = B(u+1)h0[left by prev vmcnt] + B(u+1)h1 +
// A(u+1)h0 + A(u+1)h1 + B(u+2)h0 = 10 -> leaves only B(u+2)h0 in flight.
// Write-safety (1 bar/phase, max skew 1 phase): every slot overwrite is
// preceded by a barrier that all waves reached only after their last reads of
// the old content were FORCED complete by a counted lgkm in an earlier phase.

#define BM 256
#define BN 256
#define BK 64
#define NT (Kdim / BK)
#define TILE_E (256 * 64)     // 16384 ushort = 32 KB

__device__ __forceinline__ void gload_lds16(const ushort* g, ushort* l) {
  __builtin_amdgcn_global_load_lds((const __attribute__((address_space(1))) void*)g,
                                   (__attribute__((address_space(3))) void*)l,
                                   16, 0, 0);
}

#define STAGE(dst, mat, goff, h, kcol)                                              \
  do {                                                                              \
    gload_lds16((mat) + (size_t)goff[(h)*2 + 0] + (kcol), (dst) + loff[(h)*2 + 0]); \
    gload_lds16((mat) + (size_t)goff[(h)*2 + 1] + (kcol), (dst) + loff[(h)*2 + 1]); \
  } while (0)

#define BAR()                                   \
  do {                                          \
    asm volatile("" ::: "memory");              \
    __builtin_amdgcn_s_barrier();               \
    asm volatile("" ::: "memory");              \
  } while (0)

#define LGKM(n)                                                   \
  do {                                                            \
    asm volatile("s_waitcnt lgkmcnt(" #n ")" ::: "memory");       \
    __builtin_amdgcn_sched_barrier(0);                            \
  } while (0)

#define MFMA16(base, AF, BFR)                                                    \
  do {                                                                           \
    __builtin_amdgcn_s_setprio(1);                                               \
    _Pragma("unroll")                                                            \
    for (int m2 = 0; m2 < 2; ++m2)                                               \
      _Pragma("unroll")                                                          \
      for (int ni = 0; ni < 4; ++ni)                                             \
        _Pragma("unroll")                                                        \
        for (int kk = 0; kk < 2; ++kk)                                           \
          acc[(base) + m2][ni] = __builtin_amdgcn_mfma_f32_16x16x32_bf16(        \
              AF[m2][kk], BFR[ni][kk], acc[(base) + m2][ni], 0, 0, 0);           \
    __builtin_amdgcn_s_setprio(0);                                               \
  } while (0)

#define RD_AF(dst, aR0_, aR1_, r0)                                  \
  do {                                                              \
    _Pragma("unroll")                                               \
    for (int m2 = 0; m2 < 2; ++m2) {                                \
      dst[m2][0] = *(const bf16x8*)((aR0_) + ((r0) + m2) * 1024);   \
      dst[m2][1] = *(const bf16x8*)((aR1_) + ((r0) + m2) * 1024);   \
    }                                                               \
  } while (0)

#define RD_BFR(dst, bR0_, bR1_)                                     \
  do {                                                              \
    _Pragma("unroll")                                               \
    for (int ni = 0; ni < 4; ++ni) {                                \
      dst[ni][0] = *(const bf16x8*)((bR0_) + ni * 1024);            \
      dst[ni][1] = *(const bf16x8*)((bR1_) + ni * 1024);            \
    }                                                               \
  } while (0)

// One K-tile. SA/SB: current slots; DA: A(u+1) target slot; OB: B(u+1) slot.
// BFR_C: this tile's B frags; BFR_N: next tile's (filled in q3). DO_A/DO_B/DO_N
// are compile-time 0/1. VMQ2: vmcnt string at q2-end.
#define TILE_BODY(SA, SB, DA, OB, BFR_C, BFR_N, kA, kB, DO_A, DO_B, VMQ2, DO_N) \
  do {                                                                          \
    const ushort* aR0 = (SA) + laneAOff + xo0;                                  \
    const ushort* aR1 = (SA) + laneAOff + xo1;                                  \
    /* q0: read af1; stage A(u+1)h0; MFMA quad0 (af0 in afA, bfr in BFR_C) */   \
    RD_AF(afB, aR0, aR1, 2);                                                    \
    if (DO_A) STAGE((DA), A, goffA, 0, (kA));                                   \
    LGKM(4);                                                                    \
    MFMA16(0, afA, BFR_C);                                                      \
    BAR();                                                                      \
    /* q1: read af2; stage A(u+1)h1; MFMA quad1 */                              \
    RD_AF(afA, aR0, aR1, 4);                                                    \
    if (DO_A) STAGE((DA), A, goffA, 1, (kA));                                   \
    LGKM(4);                                                                    \
    MFMA16(2, afB, BFR_C);                                                      \
    BAR();                                                                      \
    /* q2: read af3; stage B(u+2)h0; MFMA quad2; vmcnt checkpoint */            \
    RD_AF(afB, aR0, aR1, 6);                                                    \
    if (DO_B) STAGE((SB), B, goffB, 0, (kB));                                   \
    LGKM(4);                                                                    \
    MFMA16(4, afA, BFR_C);                                                      \
    asm volatile("s_waitcnt " VMQ2 ::: "memory");                               \
    BAR();                                                                      \
    /* q3: read bfr'(8)+af0'(4) for tile u+1; stage B(u+2)h1; MFMA quad3 */     \
    if (DO_N) {                                                                 \
      const ushort* bN0 = (OB) + laneBOff + xo0;                                \
      const ushort* bN1 = (OB) + laneBOff + xo1;                                \
      RD_BFR(BFR_N, bN0, bN1);                                                  \
      const ushort* aN0 = (DA) + laneAOff + xo0;                                \
      const ushort* aN1 = (DA) + laneAOff + xo1;                                \
      RD_AF(afA, aN0, aN1, 0);                                                  \
      if (DO_B) STAGE((SB), B, goffB, 1, (kB));                                 \
      LGKM(12);                                                                 \
    } else {                                                                    \
      LGKM(0);                                                                  \
    }                                                                           \
    MFMA16(6, afB, BFR_C);                                                      \
    BAR();                                                                      \
  } while (0)

__global__ __launch_bounds__(512, 2) void gemm256(const ushort* __restrict__ A,
                                                  const ushort* __restrict__ B,
                                                  float* __restrict__ C,
                                                  const float* __restrict__ scalep,
                                                  const float* __restrict__ wscale2p) {
  extern __shared__ __align__(16) ushort lds[];   // 131072 B
  const int tid = threadIdx.x;
  const int wave = tid >> 6;
  const int lane = tid & 63;
  const int wm = wave >> 2;
  const int wn = wave & 3;
  const int fr = lane & 15;
  const int fq = lane >> 4;

  const int wg = blockIdx.x;
  const int swz = (wg & 7) * 32 + (wg >> 3);      // 256 % 8 == 0 -> bijective
  const int m0 = (swz >> 4) * BM;
  const int n0 = (swz & 15) * BN;

  f32x4 acc[8][4];
#pragma unroll
  for (int i = 0; i < 8; ++i)
#pragma unroll
    for (int j = 0; j < 4; ++j) acc[i][j] = (f32x4){0.f, 0.f, 0.f, 0.f};

  ushort* A0s = lds;
  ushort* A1s = lds + TILE_E;
  ushort* B0s = lds + 2 * TILE_E;
  ushort* B1s = lds + 3 * TILE_E;

  int goffA[4], goffB[4], loff[4];
#pragma unroll
  for (int h = 0; h < 2; ++h)
#pragma unroll
    for (int rr = 0; rr < 2; ++rr) {
      const int idx = h * 2 + rr;
      const int rowb = h * 128 + rr * 64 + wave * 8;
      const int trow = rowb + (lane >> 3);
      const int sc = (lane & 7) ^ (trow & 7);
      goffA[idx] = (m0 + trow) * Kdim + sc * 8;
      goffB[idx] = (n0 + trow) * Kdim + sc * 8;
      loff[idx] = rowb * 64;
    }

  const int laneAOff = (wm * 128 + fr) * 64;
  const int laneBOff = (wn * 64 + fr) * 64;
  const int xo0 = (fq ^ (fr & 7)) * 8;
  const int xo1 = ((4 + fq) ^ (fr & 7)) * 8;

  // ---- prologue: A(0), B(0), B(1) staged; pre-read af0(0)+bfr(0) (12 reads,
  //      forced by q0's lgkm(4)) ----
  STAGE(A0s, A, goffA, 0, 0);  STAGE(A0s, A, goffA, 1, 0);
  STAGE(B0s, B, goffB, 0, 0);  STAGE(B0s, B, goffB, 1, 0);
  STAGE(B1s, B, goffB, 0, BK); STAGE(B1s, B, goffB, 1, BK);
  asm volatile("s_waitcnt vmcnt(4)" ::: "memory");   // A(0),B(0) landed; B(1) flies
  BAR();

  bf16x8 afA[2][2], afB[2][2], bfrE[4][2], bfrO[4][2];
  {
    const ushort* bR0 = B0s + laneBOff + xo0;
    const ushort* bR1 = B0s + laneBOff + xo1;
    RD_BFR(bfrE, bR0, bR1);
    const ushort* a0 = A0s + laneAOff + xo0;
    const ushort* a1 = A0s + laneAOff + xo1;
    RD_AF(afA, a0, a1, 0);
  }

  // ---- main loop: tiles 0..61, unrolled x2 (parity-static register sets) ----
  for (int it = 0; it < 31; ++it) {
    const int u = 2 * it;
    TILE_BODY(A0s, B0s, A1s, B1s, bfrE, bfrO,
              (u + 1) * BK, (u + 2) * BK, 1, 1, "vmcnt(2)", 1);
    TILE_BODY(A1s, B1s, A0s, B0s, bfrO, bfrE,
              (u + 2) * BK, (u + 3) * BK, 1, 1, "vmcnt(2)", 1);
  }
  // ---- tails: u=62 (even slots; stage A(63) only, drain vm), u=63 ----
  TILE_BODY(A0s, B0s, A1s, B1s, bfrE, bfrO, 63 * BK, 0, 1, 0, "vmcnt(0)", 1);
  TILE_BODY(A1s, B1s, A0s, B0s, bfrO, bfrE, 0, 0, 0, 0, "vmcnt(0)", 0);

  const float alpha = scalep[0] * wscale2p[0];
#pragma unroll
  for (int mi = 0; mi < 8; ++mi)
#pragma unroll
    for (int ni = 0; ni < 4; ++ni) {
      const int col = n0 + wn * 64 + ni * 16 + fr;
      const int rbase = m0 + wm * 128 + mi * 16 + fq * 4;
#pragma unroll
      for (int r = 0; r < 4; ++r)
        __builtin_nontemporal_store(alpha * acc[mi][ni][r],
                                    &C[(size_t)(rbase + r) * Ndim + col]);
    }
}

// ---------------- launcher ----------------

extern "C" void kernel_launch(void* const* d_in, const int* in_sizes, int n_in,
                              void* d_out, int out_size, void* d_ws, size_t ws_size,
                              hipStream_t stream) {
  const float* x       = (const float*)d_in[0];
  const int*   w       = (const int*)d_in[1];
  const float* wscale  = (const float*)d_in[2];
  const float* wscale2 = (const float*)d_in[3];
  const float* scale   = (const float*)d_in[4];
  float* out = (float*)d_out;

  ushort* a_deq = (ushort*)d_ws;                       // 32 MB
  ushort* b_deq = a_deq + (size_t)Mdim * Kdim;         // 32 MB

  silu_quant_kernel<<<Mdim, 256, 0, stream>>>(x, a_deq, scale);
  wdeq_kernel<<<Ndim, 256, 0, stream>>>(w, wscale, b_deq);

  (void)hipFuncSetAttribute((const void*)gemm256, hipFuncAttributeMaxDynamicSharedMemorySize, 131072);
  gemm256<<<(Mdim / BM) * (Ndim / BN), 512, 131072, stream>>>(a_deq, b_deq, out, scale, wscale2);
}

// Round 8
// 158.033 us; speedup vs baseline: 1.4608x; 1.4608x over previous
//
#include <hip/hip_runtime.h>
#include <math.h>

typedef unsigned int uint;
typedef unsigned short ushort;
typedef __attribute__((ext_vector_type(8))) short bf16x8;
typedef __attribute__((ext_vector_type(4))) float f32x4;

static constexpr int Mdim = 4096;
static constexpr int Ndim = 4096;
static constexpr int Kdim = 4096;
static constexpr int Hdim = 4096;

// ---------------- numerics helpers ----------------

__device__ __forceinline__ float fp8_round(float v) {
  float a = fabsf(v);
  float q;
  if (a >= 0x1p-6f) {           // normal range: quantum 2^(e-3)
    uint u = __float_as_uint(a);
    int e = (int)(u >> 23) - 127;
    float quant = __uint_as_float((uint)(e - 3 + 127) << 23);
    q = rintf(a / quant) * quant;
    q = fminf(q, 448.f);
  } else {                      // subnormal: quantum 2^-9
    q = rintf(a * 512.f) * 0x1p-9f;
  }
  return copysignf(q, v);
}

__device__ __forceinline__ float e2m1_round(float t) {
  float a = fabsf(t);
  float q;
  if (a <= 0.25f) q = 0.f;
  else if (a <= 0.75f) q = 0.5f;
  else if (a <= 1.25f) q = 1.f;
  else if (a <= 1.75f) q = 1.5f;
  else if (a <= 2.5f)  q = 2.f;
  else if (a <= 3.5f)  q = 3.f;
  else if (a <= 5.f)   q = 4.f;
  else                 q = 6.f;
  return copysignf(q, t);
}

__device__ __forceinline__ float e2m1_decode(uint c) {
  uint m = c & 7u;
  float v;
  if (m == 0u) v = 0.f;
  else if (m == 1u) v = 0.5f;
  else v = __uint_as_float(((126u + (m >> 1)) << 23) | ((m & 1u) << 22));
  return (c & 8u) ? -v : v;
}

// ---------------- merged prep kernel ----------------
// blocks [0, 4096): SiLU-mul + NVFP4 fake-quant row of a_deq
// blocks [4096, 8192): weight nibble unpack + fp8-scale dequant row of b_deq

__global__ void prep_kernel(const float* __restrict__ x, const int* __restrict__ w,
                            const float* __restrict__ wscale,
                            const float* __restrict__ scalep,
                            ushort* __restrict__ a_deq, ushort* __restrict__ b_deq) {
  const int b = blockIdx.x;
  if (b < Mdim) {
    // ---- SiLU-mul + quant ----
    const int row = b;
    const int blk = threadIdx.x;                // 16-elem block index 0..255
    const float gs = 1.0f / scalep[0];
    const float c6 = gs / 6.0f;
    const float* gp = x + (size_t)row * (2 * Hdim) + blk * 16;
    const float* up = gp + Hdim;
    float y[16];
    float amax = 0.f;
#pragma unroll
    for (int i = 0; i < 4; ++i) {
      float4 gv = ((const float4*)gp)[i];
      float4 uv = ((const float4*)up)[i];
      float ga[4] = {gv.x, gv.y, gv.z, gv.w};
      float ua[4] = {uv.x, uv.y, uv.z, uv.w};
#pragma unroll
      for (int j = 0; j < 4; ++j) {
        float xv = ga[j];
        float sig = 1.0f / (1.0f + expf(-xv));
        float yy = xv * sig * ua[j];
        y[i * 4 + j] = yy;
        amax = fmaxf(amax, fabsf(yy));
      }
    }
    const float sf = fp8_round(amax * c6);
    uint outp[8];
    if (sf > 0.f) {
      const float inv = gs / sf;
#pragma unroll
      for (int i = 0; i < 8; ++i) {
        float t0 = fminf(fmaxf(y[2 * i] * inv, -6.f), 6.f);
        float t1 = fminf(fmaxf(y[2 * i + 1] * inv, -6.f), 6.f);
        float d0 = e2m1_round(t0) * sf;
        float d1 = e2m1_round(t1) * sf;
        outp[i] = (__float_as_uint(d0) >> 16) | ((__float_as_uint(d1) >> 16) << 16);
      }
    } else {
#pragma unroll
      for (int i = 0; i < 8; ++i) outp[i] = 0u;
    }
    uint4* dst = (uint4*)(a_deq + (size_t)row * Hdim + blk * 16);
    dst[0] = (uint4){outp[0], outp[1], outp[2], outp[3]};
    dst[1] = (uint4){outp[4], outp[5], outp[6], outp[7]};
  } else {
    // ---- weight dequant ----
    const int n = b - Mdim;
    const int blk = threadIdx.x;                // 16-k block index 0..255
    const int4* wp = (const int4*)(w + (size_t)n * (Hdim / 2) + blk * 8);
    int4 w0 = wp[0], w1 = wp[1];
    int wb[8] = {w0.x, w0.y, w0.z, w0.w, w1.x, w1.y, w1.z, w1.w};
    const float ws = fp8_round(wscale[(size_t)n * (Hdim / 16) + blk]);
    uint outp[8];
#pragma unroll
    for (int i = 0; i < 8; ++i) {
      uint byte = (uint)wb[i] & 0xFFu;
      float vlo = e2m1_decode(byte & 15u) * ws;   // low nibble = even k
      float vhi = e2m1_decode(byte >> 4) * ws;
      outp[i] = (__float_as_uint(vlo) >> 16) | ((__float_as_uint(vhi) >> 16) << 16);
    }
    uint4* dst = (uint4*)(b_deq + (size_t)n * Hdim + blk * 16);
    dst[0] = (uint4){outp[0], outp[1], outp[2], outp[3]};
    dst[1] = (uint4){outp[4], outp[5], outp[6], outp[7]};
  }
}

// ---------------- kernel 3: 256x256 bf16 GEMM (round-3 best: pipelined ds_reads
// + triple-buffered A, compiler-scheduled) ----------------
// 8 waves (2M x 4N), BK=64. LDS 160 KB: A x3 (96 KB) + B x2 (64 KB).
// Phase p issues phase p+1's A-frag ds_reads BEFORE its MFMA burst. Stages:
// A(kt+2)h0@ph0, h1@ph1, B(kt+2)h0@ph2, h1@ph3. Checkpoint vmcnt(6) at end of
// ph2 forces tile kt+1 landed a full K-tile after issue.

#define BM 256
#define BN 256
#define BK 64
#define NT (Kdim / BK)
#define TILE_E (256 * 64)     // 16384 ushort = 32 KB

__device__ __forceinline__ void gload_lds16(const ushort* g, ushort* l) {
  __builtin_amdgcn_global_load_lds((const __attribute__((address_space(1))) void*)g,
                                   (__attribute__((address_space(3))) void*)l,
                                   16, 0, 0);
}

#define BAR()                                   \
  do {                                          \
    asm volatile("" ::: "memory");              \
    __builtin_amdgcn_s_barrier();               \
    asm volatile("" ::: "memory");              \
  } while (0)

__global__ __launch_bounds__(512, 2) void gemm256(const ushort* __restrict__ A,
                                                  const ushort* __restrict__ B,
                                                  float* __restrict__ C,
                                                  const float* __restrict__ scalep,
                                                  const float* __restrict__ wscale2p) {
  extern __shared__ __align__(16) ushort lds[];   // 163840 B
  const int tid = threadIdx.x;
  const int wave = tid >> 6;
  const int lane = tid & 63;
  const int wm = wave >> 2;
  const int wn = wave & 3;
  const int fr = lane & 15;
  const int fq = lane >> 4;

  const int wg = blockIdx.x;
  const int swz = (wg & 7) * 32 + (wg >> 3);      // 256 % 8 == 0 -> bijective
  const int m0 = (swz >> 4) * BM;
  const int n0 = (swz & 15) * BN;

  f32x4 acc[8][4];
#pragma unroll
  for (int i = 0; i < 8; ++i)
#pragma unroll
    for (int j = 0; j < 4; ++j) acc[i][j] = (f32x4){0.f, 0.f, 0.f, 0.f};

  // rotating LDS slot pointers
  ushort* pA0 = lds;                  // slot 0
  ushort* pA1 = lds + TILE_E;         // slot 1
  ushort* pA2 = lds + 2 * TILE_E;     // slot 2 (stage target)
  ushort* pB0 = lds + 3 * TILE_E;     // B read slot (tile kt)
  ushort* pB1 = lds + 4 * TILE_E;     // B other (tile kt+1)

  // staging per-thread geometry (invariant): row = h*128 + rr*64 + wave*8 + lane/8
  int goffA[4], goffB[4], loff[4];
#pragma unroll
  for (int h = 0; h < 2; ++h)
#pragma unroll
    for (int rr = 0; rr < 2; ++rr) {
      const int idx = h * 2 + rr;
      const int rowb = h * 128 + rr * 64 + wave * 8;
      const int trow = rowb + (lane >> 3);
      const int sc = (lane & 7) ^ (trow & 7);
      goffA[idx] = (m0 + trow) * Kdim + sc * 8;
      goffB[idx] = (n0 + trow) * Kdim + sc * 8;
      loff[idx] = rowb * 64;
    }

#define STAGE_A(h, kcol)                                                  \
  do {                                                                    \
    gload_lds16(A + (size_t)goffA[(h)*2 + 0] + (kcol), pA2 + loff[(h)*2 + 0]); \
    gload_lds16(A + (size_t)goffA[(h)*2 + 1] + (kcol), pA2 + loff[(h)*2 + 1]); \
  } while (0)
#define STAGE_B(h, kcol)                                                  \
  do {                                                                    \
    gload_lds16(B + (size_t)goffB[(h)*2 + 0] + (kcol), pB0 + loff[(h)*2 + 0]); \
    gload_lds16(B + (size_t)goffB[(h)*2 + 1] + (kcol), pB0 + loff[(h)*2 + 1]); \
  } while (0)

  // fragment read geometry
  const int laneAOff = (wm * 128 + fr) * 64;
  const int laneBOff = (wn * 64 + fr) * 64;
  const int xo0 = (fq ^ (fr & 7)) * 8;            // kk = 0
  const int xo1 = ((4 + fq) ^ (fr & 7)) * 8;      // kk = 1

  // ---- prologue: stage A0,B0,A1,B1; force A0,B0; preload bfr + af0 ----
  {
    ushort* sv = pA2;
    pA2 = pA0; STAGE_A(0, 0); STAGE_A(1, 0);            // A tile0 -> slot0
    STAGE_B(0, 0); STAGE_B(1, 0);                       // B tile0 -> Bslot0
    pA2 = pA1; STAGE_A(0, BK); STAGE_A(1, BK);          // A tile1 -> slot1
    { ushort* t = pB0; pB0 = pB1; STAGE_B(0, BK); STAGE_B(1, BK); pB0 = t; }  // B tile1 -> Bslot1
    pA2 = sv;
  }
  asm volatile("s_waitcnt vmcnt(8)" ::: "memory");   // tile0 landed; tile1 in flight
  BAR();

  bf16x8 af0[2][2], bfr[4][2];
  {
    const ushort* aR0 = pA0 + laneAOff + xo0;
    const ushort* aR1 = pA0 + laneAOff + xo1;
    const ushort* bR0 = pB0 + laneBOff + xo0;
    const ushort* bR1 = pB0 + laneBOff + xo1;
#pragma unroll
    for (int ni = 0; ni < 4; ++ni) {
      bfr[ni][0] = *(const bf16x8*)(bR0 + ni * 1024);
      bfr[ni][1] = *(const bf16x8*)(bR1 + ni * 1024);
    }
#pragma unroll
    for (int m2 = 0; m2 < 2; ++m2) {
      af0[m2][0] = *(const bf16x8*)(aR0 + m2 * 1024);
      af0[m2][1] = *(const bf16x8*)(aR1 + m2 * 1024);
    }
  }

  for (int kt = 0; kt < NT; ++kt) {
    const int kc = (kt + 2) * BK;
    const bool stg = (kt + 2) < NT;
    const bool nxt = (kt + 1) < NT;
    const ushort* aR0 = pA0 + laneAOff + xo0;
    const ushort* aR1 = pA0 + laneAOff + xo1;
    bf16x8 af1[2][2], af2[2][2], af3[2][2];

    // ---- ph0: read af1; stage A(kt+2)h0; MFMA rows 0-1 ----
#pragma unroll
    for (int m2 = 0; m2 < 2; ++m2) {
      af1[m2][0] = *(const bf16x8*)(aR0 + (2 + m2) * 1024);
      af1[m2][1] = *(const bf16x8*)(aR1 + (2 + m2) * 1024);
    }
    if (stg) STAGE_A(0, kc);
    BAR();
    __builtin_amdgcn_s_setprio(1);
#pragma unroll
    for (int m2 = 0; m2 < 2; ++m2)
#pragma unroll
      for (int ni = 0; ni < 4; ++ni)
#pragma unroll
        for (int kk = 0; kk < 2; ++kk)
          acc[m2][ni] = __builtin_amdgcn_mfma_f32_16x16x32_bf16(af0[m2][kk], bfr[ni][kk],
                                                                acc[m2][ni], 0, 0, 0);
    __builtin_amdgcn_s_setprio(0);
    BAR();

    // ---- ph1: read af2; stage A(kt+2)h1; MFMA rows 2-3 ----
#pragma unroll
    for (int m2 = 0; m2 < 2; ++m2) {
      af2[m2][0] = *(const bf16x8*)(aR0 + (4 + m2) * 1024);
      af2[m2][1] = *(const bf16x8*)(aR1 + (4 + m2) * 1024);
    }
    if (stg) STAGE_A(1, kc);
    BAR();
    __builtin_amdgcn_s_setprio(1);
#pragma unroll
    for (int m2 = 0; m2 < 2; ++m2)
#pragma unroll
      for (int ni = 0; ni < 4; ++ni)
#pragma unroll
        for (int kk = 0; kk < 2; ++kk)
          acc[2 + m2][ni] = __builtin_amdgcn_mfma_f32_16x16x32_bf16(af1[m2][kk], bfr[ni][kk],
                                                                    acc[2 + m2][ni], 0, 0, 0);
    __builtin_amdgcn_s_setprio(0);
    BAR();

    // ---- ph2: read af3; stage B(kt+2)h0; MFMA rows 4-5; vmcnt checkpoint ----
#pragma unroll
    for (int m2 = 0; m2 < 2; ++m2) {
      af3[m2][0] = *(const bf16x8*)(aR0 + (6 + m2) * 1024);
      af3[m2][1] = *(const bf16x8*)(aR1 + (6 + m2) * 1024);
    }
    if (stg) STAGE_B(0, kc);
    BAR();
    __builtin_amdgcn_s_setprio(1);
#pragma unroll
    for (int m2 = 0; m2 < 2; ++m2)
#pragma unroll
      for (int ni = 0; ni < 4; ++ni)
#pragma unroll
        for (int kk = 0; kk < 2; ++kk)
          acc[4 + m2][ni] = __builtin_amdgcn_mfma_f32_16x16x32_bf16(af2[m2][kk], bfr[ni][kk],
                                                                    acc[4 + m2][ni], 0, 0, 0);
    __builtin_amdgcn_s_setprio(0);
    if (stg) asm volatile("s_waitcnt vmcnt(6)" ::: "memory");  // forces tile kt+1 landed
    else     asm volatile("s_waitcnt vmcnt(0)" ::: "memory");
    BAR();

    // ---- ph3: stage B(kt+2)h1; MFMA rows 6-7; then read next tile's bfr+af0 ----
    if (stg) STAGE_B(1, kc);
    BAR();
    __builtin_amdgcn_s_setprio(1);
#pragma unroll
    for (int m2 = 0; m2 < 2; ++m2)
#pragma unroll
      for (int ni = 0; ni < 4; ++ni)
#pragma unroll
        for (int kk = 0; kk < 2; ++kk)
          acc[6 + m2][ni] = __builtin_amdgcn_mfma_f32_16x16x32_bf16(af3[m2][kk], bfr[ni][kk],
                                                                    acc[6 + m2][ni], 0, 0, 0);
    __builtin_amdgcn_s_setprio(0);
    if (nxt) {
      const ushort* aN0 = pA1 + laneAOff + xo0;
      const ushort* aN1 = pA1 + laneAOff + xo1;
      const ushort* bN0 = pB1 + laneBOff + xo0;
      const ushort* bN1 = pB1 + laneBOff + xo1;
#pragma unroll
      for (int ni = 0; ni < 4; ++ni) {
        bfr[ni][0] = *(const bf16x8*)(bN0 + ni * 1024);
        bfr[ni][1] = *(const bf16x8*)(bN1 + ni * 1024);
      }
#pragma unroll
      for (int m2 = 0; m2 < 2; ++m2) {
        af0[m2][0] = *(const bf16x8*)(aN0 + m2 * 1024);
        af0[m2][1] = *(const bf16x8*)(aN1 + m2 * 1024);
      }
    }
    BAR();

    // rotate slots: A three-way, B swap
    { ushort* t = pA0; pA0 = pA1; pA1 = pA2; pA2 = t; }
    { ushort* t = pB0; pB0 = pB1; pB1 = t; }
  }

  const float alpha = scalep[0] * wscale2p[0];
#pragma unroll
  for (int mi = 0; mi < 8; ++mi)
#pragma unroll
    for (int ni = 0; ni < 4; ++ni) {
      const int col = n0 + wn * 64 + ni * 16 + fr;
      const int rbase = m0 + wm * 128 + mi * 16 + fq * 4;
#pragma unroll
      for (int r = 0; r < 4; ++r)
        C[(size_t)(rbase + r) * Ndim + col] = alpha * acc[mi][ni][r];
    }
}

// ---------------- launcher ----------------

extern "C" void kernel_launch(void* const* d_in, const int* in_sizes, int n_in,
                              void* d_out, int out_size, void* d_ws, size_t ws_size,
                              hipStream_t stream) {
  const float* x       = (const float*)d_in[0];
  const int*   w       = (const int*)d_in[1];
  const float* wscale  = (const float*)d_in[2];
  const float* wscale2 = (const float*)d_in[3];
  const float* scale   = (const float*)d_in[4];
  float* out = (float*)d_out;

  ushort* a_deq = (ushort*)d_ws;                       // 32 MB
  ushort* b_deq = a_deq + (size_t)Mdim * Kdim;         // 32 MB

  prep_kernel<<<Mdim + Ndim, 256, 0, stream>>>(x, w, wscale, scale, a_deq, b_deq);

  (void)hipFuncSetAttribute((const void*)gemm256, hipFuncAttributeMaxDynamicSharedMemorySize, 163840);
  gemm256<<<(Mdim / BM) * (Ndim / BN), 512, 163840, stream>>>(a_deq, b_deq, out, scale, wscale2);
}